// Round 1
// baseline (1044.437 us; speedup 1.0000x reference)
//
#include <hip/hip_runtime.h>
#include <math.h>

#define KDIM 8192
#define HC 4
#define ROWS_PER_BLOCK 16
#define THREADS 256
#define NCHUNK (KDIM / 256)   // 32 chunks of 256 k each

static __device__ __forceinline__ float f4get(float4 v, int i) {
    return i == 0 ? v.x : i == 1 ? v.y : i == 2 ? v.z : v.w;
}

__global__ __launch_bounds__(THREADS, 2)
void mhc_coeffs_kernel(const float* __restrict__ x,
                       const float* __restrict__ phi,
                       const float* __restrict__ bvec,
                       const float* __restrict__ a_pre,
                       const float* __restrict__ a_post,
                       const float* __restrict__ a_res,
                       float* __restrict__ out, int nrows)
{
    const int lane = threadIdx.x & 63;
    const int w    = threadIdx.x >> 6;                       // wave 0..3
    const int rowbase = blockIdx.x * ROWS_PER_BLOCK + w * 4; // 4 rows per wave

    // acc[r][0..23] = dot(x_row, phi[:,j]) partials; acc[r][24] = sum(x^2) partial
    float acc[4][25];
#pragma unroll
    for (int r = 0; r < 4; ++r)
#pragma unroll
        for (int j = 0; j < 25; ++j) acc[r][j] = 0.f;

    // lane l owns k = c*256 + l*4 .. +3 for chunk c
    const float4* xp0 = (const float4*)(x + (size_t)(rowbase + 0) * KDIM) + lane;
    const float4* xp1 = (const float4*)(x + (size_t)(rowbase + 1) * KDIM) + lane;
    const float4* xp2 = (const float4*)(x + (size_t)(rowbase + 2) * KDIM) + lane;
    const float4* xp3 = (const float4*)(x + (size_t)(rowbase + 3) * KDIM) + lane;
    // phi row k starts at float4 index k*6 (24 floats = 6 float4 per row)
    const float4* pp = (const float4*)phi + (size_t)lane * 24; // = row(lane*4)*6

    float4 xc0 = xp0[0], xc1 = xp1[0], xc2 = xp2[0], xc3 = xp3[0];

    auto do_chunk = [&](const float4* pb, float4 v0, float4 v1, float4 v2, float4 v3) {
#pragma unroll
        for (int kk = 0; kk < 4; ++kk) {
            const float x0 = f4get(v0, kk), x1 = f4get(v1, kk);
            const float x2 = f4get(v2, kk), x3 = f4get(v3, kk);
#pragma unroll
            for (int jj = 0; jj < 6; ++jj) {
                const float4 p = pb[kk * 6 + jj];
#pragma unroll
                for (int u = 0; u < 4; ++u) {
                    const float pv = f4get(p, u);
                    const int j = jj * 4 + u;
                    acc[0][j] = fmaf(x0, pv, acc[0][j]);
                    acc[1][j] = fmaf(x1, pv, acc[1][j]);
                    acc[2][j] = fmaf(x2, pv, acc[2][j]);
                    acc[3][j] = fmaf(x3, pv, acc[3][j]);
                }
            }
            acc[0][24] = fmaf(x0, x0, acc[0][24]);
            acc[1][24] = fmaf(x1, x1, acc[1][24]);
            acc[2][24] = fmaf(x2, x2, acc[2][24]);
            acc[3][24] = fmaf(x3, x3, acc[3][24]);
        }
    };

    // main loop: prefetch next chunk's x while computing current (no LDS, no barriers)
    for (int c = 0; c < NCHUNK - 1; ++c) {
        const int o = (c + 1) * 64;
        float4 xn0 = xp0[o], xn1 = xp1[o], xn2 = xp2[o], xn3 = xp3[o];
        do_chunk(pp + (size_t)c * 1536, xc0, xc1, xc2, xc3);
        xc0 = xn0; xc1 = xn1; xc2 = xn2; xc3 = xn3;
    }
    do_chunk(pp + (size_t)(NCHUNK - 1) * 1536, xc0, xc1, xc2, xc3);

    // k-reduction across the 64 lanes (butterfly: every lane ends with full sums)
#pragma unroll
    for (int r = 0; r < 4; ++r)
#pragma unroll
        for (int j = 0; j < 25; ++j) {
            float v = acc[r][j];
            v += __shfl_xor(v, 1);
            v += __shfl_xor(v, 2);
            v += __shfl_xor(v, 4);
            v += __shfl_xor(v, 8);
            v += __shfl_xor(v, 16);
            v += __shfl_xor(v, 32);
            acc[r][j] = v;
        }

    // ---- epilogue: lane = r*16 + (i*4+j) of the 4x4 sinkhorn matrix ----
    const int r = lane >> 4;
    const int e = lane & 15;
    const int row = rowbase + r;

    // static-index row select (no runtime array indexing -> stays in VGPRs)
    float rs[25];
#pragma unroll
    for (int j = 0; j < 25; ++j)
        rs[j] = (r == 0) ? acc[0][j] : (r == 1) ? acc[1][j] : (r == 2) ? acc[2][j] : acc[3][j];

    const float invr = 1.0f / sqrtf(rs[24] * (1.0f / (float)KDIM) + 1e-6f);

    // res logit for this lane's element: mix[8+e]*alpha_res + b[8+e]
    float dres = rs[8];
#pragma unroll
    for (int m = 1; m < 16; ++m) dres = (e == m) ? rs[8 + m] : dres;
    const float lg = fmaf(dres * invr, a_res[0], bvec[8 + e]);

    // softmax over j (lanes ^1, ^2 within the 4-lane row group)
    float mx = fmaxf(lg, __shfl_xor(lg, 1));
    mx = fmaxf(mx, __shfl_xor(mx, 2));
    const float ex = expf(lg - mx);
    float sm = ex + __shfl_xor(ex, 1);
    sm += __shfl_xor(sm, 2);
    float mat = ex / sm + 1e-6f;

    // col-normalize (sum over i: lanes ^4, ^8), then 7x (row-norm; col-norm)
    float cs = mat + __shfl_xor(mat, 4);
    cs += __shfl_xor(cs, 8);
    mat = mat / (cs + 1e-6f);
#pragma unroll
    for (int t = 0; t < 7; ++t) {
        float rsum = mat + __shfl_xor(mat, 1);
        rsum += __shfl_xor(rsum, 2);
        mat = mat / (rsum + 1e-6f);
        float csum = mat + __shfl_xor(mat, 4);
        csum += __shfl_xor(csum, 8);
        mat = mat / (csum + 1e-6f);
    }
    // h_res at offset nrows*8 (after h_pre nrows*4 and h_post nrows*4), coalesced
    out[(size_t)nrows * 8 + (size_t)row * 16 + e] = mat;

    if (e < 8) {
        float dpp = rs[0];
#pragma unroll
        for (int m = 1; m < 8; ++m) dpp = (e == m) ? rs[m] : dpp;
        if (e < 4) {
            const float z = fmaf(dpp * invr, a_pre[0], bvec[e]);
            out[(size_t)row * 4 + e] = 1.0f / (1.0f + expf(-z)) + 0.01f;
        } else {
            const float z = fmaf(dpp * invr, a_post[0], bvec[e]);
            out[(size_t)nrows * 4 + (size_t)row * 4 + (e - 4)] = 2.0f / (1.0f + expf(-z));
        }
    }
}

extern "C" void kernel_launch(void* const* d_in, const int* in_sizes, int n_in,
                              void* d_out, int out_size, void* d_ws, size_t ws_size,
                              hipStream_t stream) {
    const float* x     = (const float*)d_in[0];
    const float* phi   = (const float*)d_in[1];
    const float* bvec  = (const float*)d_in[2];
    const float* apre  = (const float*)d_in[3];
    const float* apost = (const float*)d_in[4];
    const float* ares  = (const float*)d_in[5];
    float* out = (float*)d_out;

    const int nrows  = in_sizes[0] / KDIM;          // 16384
    const int blocks = nrows / ROWS_PER_BLOCK;      // 1024

    mhc_coeffs_kernel<<<blocks, THREADS, 0, stream>>>(x, phi, bvec, apre, apost, ares, out, nrows);
}